// Round 6
// baseline (322.994 us; speedup 1.0000x reference)
//
#include <hip/hip_runtime.h>

// Problem constants
#define N_PTS   65536      // B*H*W = 64*32*32
#define K_CODES 1024
#define C_DIM   64
#define HW      1024
#define Q_ELEMS 4194304

// d_out layout (float32): [vq_loss(1) | quantized(4194304) | perplexity(1) | indices(65536)]
#define OUT_Q_OFF 1
#define OUT_P_OFF 4194305
#define OUT_I_OFF 4194306

// ws layout (bytes)
#define WS_HIST 0          // 1024 u32    (4096)
#define WS_SSE  4096       // 1 double    (8)
#define WS_CSUM 8192       // 1024 f32    (4096)
#define WS_CBH  16384      // 65536 bf16  (131072)
#define WS_CBL  147456     // 65536 bf16  (131072)

// Screen includes csum[k], so screen-vs-ref deviation <= ~1.4e-5
// (2x ULP(64) ref rounding + ~6e-6 split-bf16 screen error). 10x margin:
#define EPS_A 1.5e-4f

typedef float f32x16 __attribute__((ext_vector_type(16)));
typedef short bf16x8 __attribute__((ext_vector_type(8)));

__device__ __forceinline__ unsigned short bf16rn(float f) {
    unsigned int u = __float_as_uint(f);
    return (unsigned short)((u + 0x7FFFu + ((u >> 16) & 1u)) >> 16);
}
__device__ __forceinline__ float bf16tof(unsigned short h) {
    return __uint_as_float(((unsigned int)h) << 16);
}

// numpy pairwise sum (n=64): 8 accumulators striding 8, then pairwise combine.
__device__ __forceinline__ float np_pairwise_sumsq64(const float* a) {
    float r[8];
    #pragma unroll
    for (int j = 0; j < 8; ++j) r[j] = __fmul_rn(a[j], a[j]);
    #pragma unroll
    for (int i = 8; i < 64; i += 8) {
        #pragma unroll
        for (int j = 0; j < 8; ++j)
            r[j] = __fadd_rn(r[j], __fmul_rn(a[i + j], a[i + j]));
    }
    return __fadd_rn(__fadd_rn(__fadd_rn(r[0], r[1]), __fadd_rn(r[2], r[3])),
                     __fadd_rn(__fadd_rn(r[4], r[5]), __fadd_rn(r[6], r[7])));
}

// Prep: csum (pairwise f32) + split-bf16 codebook (hi/lo).
__global__ void vq_prep(const float* __restrict__ cb, float* __restrict__ csum,
                        unsigned short* __restrict__ cbh, unsigned short* __restrict__ cbl) {
    int k = blockIdx.x * 256 + threadIdx.x;   // grid = 4 blocks covers 1024
    const float* row = cb + k * C_DIM;
    csum[k] = np_pairwise_sumsq64(row);
    #pragma unroll 8
    for (int d = 0; d < C_DIM; ++d) {
        float f = row[d];
        unsigned short h = bf16rn(f);
        cbh[k * C_DIM + d] = h;
        cbl[k * C_DIM + d] = bf16rn(f - bf16tof(h));
    }
}

// Main: block = 64 points, 4 waves = (point-half x code-half). Each wave
// screens 32 points against 512 codes (16 tiles) via 3-pass split-bf16 MFMA
// with csum folded in. Ambiguous points (m2-m1 <= EPS_A) get an exact
// all-1024-code rescan, one wave per point, barrier-free, reference-bit-exact.
__global__ __launch_bounds__(256, 4) void vq_main(
        const float* __restrict__ latents,
        const float* __restrict__ cb,
        const float* __restrict__ csum,
        const unsigned short* __restrict__ cbh,
        const unsigned short* __restrict__ cbl,
        unsigned int* __restrict__ hist,
        double* __restrict__ sse,
        float* __restrict__ out) {
    __shared__ float xs[64 * 65];             // x tile, stride 65 (conflict-free)
    __shared__ float csl[1024];               // csum staged in LDS
    __shared__ float sm1[2][64], sm2[2][64];  // per code-half partials
    __shared__ int   si1[2][64];
    __shared__ int   fk[64], ambig[64], acount;

    const int tid  = threadIdx.x;
    const int lane = tid & 63, wave = tid >> 6;
    const int pg   = wave & 1;                // point-half
    const int chh  = wave >> 1;               // code-half
    const int n0 = blockIdx.x * 64;
    const int b = n0 >> 10, hw0 = n0 & 1023;
    const float* xg = latents + (size_t)b * C_DIM * HW + hw0;

    // Stage x[p][d] (64 points), coalesced global; stage csum.
    for (int i = tid; i < 64 * 64; i += 256) {
        int p = i & 63, d = i >> 6;
        xs[p * 65 + d] = xg[(size_t)d * HW + p];
    }
    for (int i = tid; i < 1024; i += 256) csl[i] = csum[i];
    if (tid == 0) acount = 0;
    __syncthreads();

    // B-frags: col = lane&31 -> point, k-dim = (lane>>5)*8 + j.
    const int l31 = lane & 31, half = lane >> 5;
    const int pb = (pg << 5) + l31;           // this lane's block-point
    bf16x8 xh[4], xl[4];
    #pragma unroll
    for (int c = 0; c < 4; ++c)
        #pragma unroll
        for (int j = 0; j < 8; ++j) {
            float f = xs[pb * 65 + c * 16 + half * 8 + j];
            unsigned short h = bf16rn(f);
            xh[c][j] = (short)h;
            xl[c][j] = (short)bf16rn(f - bf16tof(h));
        }

    float m1 = 3e38f, m2 = 3e38f;
    int i1 = 0;
    const int RC[16] = {0,1,2,3,8,9,10,11,16,17,18,19,24,25,26,27};
    const int rh4 = half * 4;                 // C/D row = RC[r] + 4*(lane>>5)
    const int kbase = chh << 9;
    const unsigned short* ah0 = cbh + ((size_t)kbase + l31) * 64 + half * 8;
    const unsigned short* al0 = cbl + ((size_t)kbase + l31) * 64 + half * 8;

    for (int t = 0; t < 16; ++t) {            // 16 code-tiles of 32 codes
        const unsigned short* ah = ah0 + (size_t)t * 2048;
        const unsigned short* al = al0 + (size_t)t * 2048;
        bf16x8 ch[4], cl[4];
        #pragma unroll
        for (int c = 0; c < 4; ++c) {
            ch[c] = *(const bf16x8*)(ah + c * 16);
            cl[c] = *(const bf16x8*)(al + c * 16);
        }
        f32x16 acc;
        #pragma unroll
        for (int r = 0; r < 16; ++r) acc[r] = 0.0f;
        #pragma unroll
        for (int c = 0; c < 4; ++c) {
            acc = __builtin_amdgcn_mfma_f32_32x32x16_bf16(ch[c], xh[c], acc, 0, 0, 0);
            acc = __builtin_amdgcn_mfma_f32_32x32x16_bf16(ch[c], xl[c], acc, 0, 0, 0);
            acc = __builtin_amdgcn_mfma_f32_32x32x16_bf16(cl[c], xh[c], acc, 0, 0, 0);
        }
        const int tb = kbase + (t << 5);
        #pragma unroll
        for (int r = 0; r < 16; ++r) {
            int k = tb + RC[r] + rh4;
            float s = __fmaf_rn(-2.0f, acc[r], csl[k]);   // ~ dist - A
            m2 = fminf(m2, fmaxf(m1, s));
            i1 = (s < m1) ? k : i1;
            m1 = fminf(m1, s);
        }
    }
    // merge the two half-wave row-sets of each point
    {
        float m1o = __shfl_xor(m1, 32, 64);
        float m2o = __shfl_xor(m2, 32, 64);
        int   i1o = __shfl_xor(i1, 32, 64);
        m2 = fminf(fminf(m2, m2o), fmaxf(m1, m1o));
        i1 = (m1o < m1) ? i1o : i1;
        m1 = fminf(m1, m1o);
        if (half == 0) { sm1[chh][pb] = m1; sm2[chh][pb] = m2; si1[chh][pb] = i1; }
    }
    __syncthreads();

    // cross code-half merge + ambiguity test (ties -> ambiguous -> rescan)
    if (tid < 64) {
        float a1 = sm1[0][tid], a2 = sm2[0][tid];
        float b1 = sm1[1][tid], b2 = sm2[1][tid];
        float mm1 = fminf(a1, b1);
        float mm2 = fminf(fmaxf(a1, b1), fminf(a2, b2));
        fk[tid] = (b1 < a1) ? si1[1][tid] : si1[0][tid];
        if (mm2 - mm1 <= EPS_A) {
            int a = atomicAdd(&acount, 1);
            ambig[a] = tid;
        }
    }
    __syncthreads();

    // Exact rescan: one wave per ambiguous point, all 1024 codes, barrier-free.
    // Reference-bit-exact: dist = fl32(fl32(A+csum[k]) - fl32(2*seqFMA)).
    for (int a = wave; a < acount; a += 4) {
        int p = ambig[a];
        const float* xrow = &xs[p * 65];      // broadcast LDS reads
        float A = np_pairwise_sumsq64(xrow);
        unsigned long long best = ~0ULL;
        for (int kk = 0; kk < 16; ++kk) {
            int k = (kk << 6) + lane;
            const float* crow = cb + (size_t)k * 64;
            float m = 0.0f;
            #pragma unroll
            for (int d = 0; d < 64; ++d) m = __fmaf_rn(xrow[d], crow[d], m);
            float D = __fsub_rn(__fadd_rn(A, csl[k]), __fmul_rn(2.0f, m));
            unsigned long long key =
                ((unsigned long long)__float_as_uint(D) << 10) | (unsigned)k;
            best = (key < best) ? key : best;
        }
        #pragma unroll
        for (int off = 32; off > 0; off >>= 1) {
            unsigned long long o = __shfl_xor(best, off, 64);
            best = (o < best) ? o : best;
        }
        if (lane == 0) fk[p] = (int)(best & 1023ULL);
    }
    __syncthreads();

    // indices + histogram + SSE (wave 0)
    if (tid < 64) {
        int myk = fk[tid];
        out[OUT_I_OFF + n0 + tid] = (float)myk;
        atomicAdd(&hist[myk], 1u);
        const float* crow = cb + (size_t)myk * 64;
        const float* xrow = &xs[tid * 65];
        double e = 0.0;
        #pragma unroll
        for (int d = 0; d < 64; ++d) {
            double df = (double)xrow[d] - (double)crow[d];
            e = fma(df, df, e);
        }
        #pragma unroll
        for (int off = 32; off > 0; off >>= 1) e += __shfl_down(e, off, 64);
        if (tid == 0) atomicAdd(sse, e);
    }
    // quantized [B,C,H,W]: coalesced 64-float rows per c
    for (int i = tid; i < 64 * 64; i += 256) {
        int p = i & 63, c = i >> 6;
        out[OUT_Q_OFF + (size_t)b * 65536 + (size_t)c * HW + hw0 + p] =
            cb[(size_t)fk[p] * 64 + c];
    }
}

// Finalize: perplexity from histogram, vq_loss from SSE.
__global__ void vq_final(const unsigned int* __restrict__ hist,
                         const double* __restrict__ sse,
                         float* __restrict__ out) {
    __shared__ double red[256];
    int t = threadIdx.x;
    double s = 0.0;
    for (int i = t; i < K_CODES; i += 256) {
        double p = (double)hist[i] / (double)N_PTS;
        s += p * log(p + 1e-10);
    }
    red[t] = s;
    __syncthreads();
    for (int w = 128; w > 0; w >>= 1) {
        if (t < w) red[t] += red[t + w];
        __syncthreads();
    }
    if (t == 0) {
        out[OUT_P_OFF] = (float)exp(-red[0]);
        out[0] = (float)(1.25 * sse[0] / (double)Q_ELEMS);
    }
}

extern "C" void kernel_launch(void* const* d_in, const int* in_sizes, int n_in,
                              void* d_out, int out_size, void* d_ws, size_t ws_size,
                              hipStream_t stream) {
    const float* latents = (const float*)d_in[0];
    const float* cb      = (const float*)d_in[1];
    float* out = (float*)d_out;
    char* ws = (char*)d_ws;

    unsigned int*   hist = (unsigned int*)(ws + WS_HIST);
    double*         sse  = (double*)(ws + WS_SSE);
    float*          csum = (float*)(ws + WS_CSUM);
    unsigned short* cbh  = (unsigned short*)(ws + WS_CBH);
    unsigned short* cbl  = (unsigned short*)(ws + WS_CBL);

    hipMemsetAsync(ws, 0, 4096 + 8, stream);  // hist + sse

    vq_prep <<<4, 256, 0, stream>>>(cb, csum, cbh, cbl);
    vq_main <<<N_PTS / 64, 256, 0, stream>>>(latents, cb, csum, cbh, cbl, hist, sse, out);
    vq_final<<<1, 256, 0, stream>>>(hist, sse, out);
}

// Round 7
// 141.231 us; speedup vs baseline: 2.2870x; 2.2870x over previous
//
#include <hip/hip_runtime.h>

// Problem constants
#define N_PTS   65536      // B*H*W = 64*32*32
#define K_CODES 1024
#define C_DIM   64
#define HW      1024
#define Q_ELEMS 4194304

// d_out layout (float32): [vq_loss(1) | quantized(4194304) | perplexity(1) | indices(65536)]
#define OUT_Q_OFF 1
#define OUT_P_OFF 4194305
#define OUT_I_OFF 4194306

// ws layout (bytes)
#define WS_HIST 0          // 1024 u32    (4096)
#define WS_SSE  4096       // 1 double    (8)
#define WS_CSUM 8192       // 1024 f32    (4096)
#define WS_CBP  16384      // packed A-frags: 32 tiles * 9 slots * 512 shorts = 294912 B

// Screen metric is w = x.c - csum/2 (argmin dist == argmax w). Proven dist-space
// thresholds EPS_A=1.5e-4 / EPS_T=4e-4 map to w-space /2:
#define EPS_A_W 7.5e-5f    // ambiguous if m2 >= m1 - EPS_A_W
#define EPS_T_W 2.0e-4f    // candidate tile if tmax >= m1 - EPS_T_W

typedef float f32x16 __attribute__((ext_vector_type(16)));
typedef short bf16x8 __attribute__((ext_vector_type(8)));

__device__ __forceinline__ unsigned short bf16rn(float f) {
    unsigned int u = __float_as_uint(f);
    return (unsigned short)((u + 0x7FFFu + ((u >> 16) & 1u)) >> 16);
}
__device__ __forceinline__ float bf16tof(unsigned short h) {
    return __uint_as_float(((unsigned int)h) << 16);
}

// numpy pairwise sum (n=64): 8 accumulators striding 8, then pairwise combine.
__device__ __forceinline__ float np_pairwise_sumsq64(const float* a) {
    float r[8];
    #pragma unroll
    for (int j = 0; j < 8; ++j) r[j] = __fmul_rn(a[j], a[j]);
    #pragma unroll
    for (int i = 8; i < 64; i += 8) {
        #pragma unroll
        for (int j = 0; j < 8; ++j)
            r[j] = __fadd_rn(r[j], __fmul_rn(a[i + j], a[i + j]));
    }
    return __fadd_rn(__fadd_rn(__fadd_rn(r[0], r[1]), __fadd_rn(r[2], r[3])),
                     __fadd_rn(__fadd_rn(r[4], r[5]), __fadd_rn(r[6], r[7])));
}

// Prep (2048 threads): csum + codebook packed into MFMA A-frag order.
// Slot layout per tile t (32 codes): slots 0..7 = chunk c hi/lo pairs
// (A[row=l31][k=c*16+half*8+j]), slot 8 = csum chunk (k=64: -csum/2 at j==0,
// half==0). Each slot = 64 lanes * 8 bf16 -> screen loads are lane*16B coalesced.
__global__ void vq_prep(const float* __restrict__ cb, float* __restrict__ csum,
                        unsigned short* __restrict__ cbp) {
    int g = blockIdx.x * 256 + threadIdx.x;   // 0..2047
    int t = g >> 6, lane = g & 63, l31 = lane & 31, half = lane >> 5;
    int row = t * 32 + l31;
    const float* r = cb + row * 64;
    float cs = np_pairwise_sumsq64(r);
    if (half == 0) csum[row] = cs;
    size_t tb = (size_t)t * 9 * 512;          // shorts per tile
    #pragma unroll
    for (int c = 0; c < 4; ++c) {
        bf16x8 h8, l8;
        #pragma unroll
        for (int j = 0; j < 8; ++j) {
            float f = r[c * 16 + half * 8 + j];
            unsigned short h = bf16rn(f);
            h8[j] = (short)h;
            l8[j] = (short)bf16rn(f - bf16tof(h));
        }
        *(bf16x8*)(cbp + tb + (size_t)(c * 2 + 0) * 512 + lane * 8) = h8;
        *(bf16x8*)(cbp + tb + (size_t)(c * 2 + 1) * 512 + lane * 8) = l8;
    }
    bf16x8 c8;
    #pragma unroll
    for (int j = 0; j < 8; ++j) c8[j] = 0;
    if (half == 0) c8[0] = (short)bf16rn(-0.5f * cs);
    *(bf16x8*)(cbp + tb + (size_t)8 * 512 + lane * 8) = c8;
}

// Main: block = 128 points, 4 waves; each wave screens its 32 points against
// all 1024 codes (32 tiles) via split-bf16 MFMA with csum folded in as K=65.
// Per-tile max (tmax) bounds the exact rescan to candidate tiles; ambiguous
// points resolved one-wave-per-point with the reference-bit-exact f32 pipeline.
__global__ __launch_bounds__(256, 2) void vq_main(
        const float* __restrict__ latents,
        const float* __restrict__ cb,
        const float* __restrict__ csum,
        const unsigned short* __restrict__ cbp,
        unsigned int* __restrict__ hist,
        double* __restrict__ sse,
        float* __restrict__ out) {
    __shared__ float xs[128 * 65];            // 33.3 KB, stride 65
    __shared__ float tmax[32 * 128];          // 16 KB per-(tile,point) screen max
    __shared__ float m1f[128];
    __shared__ int   fk[128], ambig[128], acount;
    __shared__ double dred[128];

    const int tid  = threadIdx.x;
    const int lane = tid & 63, wave = tid >> 6;
    const int n0 = blockIdx.x * 128;
    const int b = n0 >> 10, hw0 = n0 & 1023;
    const float* xg = latents + (size_t)b * C_DIM * HW + hw0;

    for (int i = tid; i < 128 * 64; i += 256) {
        int p = i & 127, d = i >> 7;
        xs[p * 65 + d] = xg[(size_t)d * HW + p];
    }
    if (tid == 0) acount = 0;
    __syncthreads();

    // B-frags: col = lane&31 -> point, k = (lane>>5)*8 + j
    const int l31 = lane & 31, half = lane >> 5;
    const int pb = (wave << 5) + l31;
    bf16x8 xh[4], xl[4], x4;
    #pragma unroll
    for (int c = 0; c < 4; ++c)
        #pragma unroll
        for (int j = 0; j < 8; ++j) {
            float f = xs[pb * 65 + c * 16 + half * 8 + j];
            unsigned short h = bf16rn(f);
            xh[c][j] = (short)h;
            xl[c][j] = (short)bf16rn(f - bf16tof(h));
        }
    #pragma unroll
    for (int j = 0; j < 8; ++j) x4[j] = 0;
    if (half == 0) x4[0] = (short)0x3F80;     // bf16(1.0) at k=64

    float m1 = -3e38f, m2 = -3e38f;
    int i1 = 0;
    const int RC[16] = {0,1,2,3,8,9,10,11,16,17,18,19,24,25,26,27};
    const int rh4 = half * 4;
    const bf16x8* base = (const bf16x8*)cbp;

    auto screen_tile = [&](int t, const bf16x8* ch, const bf16x8* cl, bf16x8 ca) {
        f32x16 accA, accB;
        #pragma unroll
        for (int r = 0; r < 16; ++r) { accA[r] = 0.0f; accB[r] = 0.0f; }
        #pragma unroll
        for (int c = 0; c < 4; ++c)
            accA = __builtin_amdgcn_mfma_f32_32x32x16_bf16(ch[c], xh[c], accA, 0, 0, 0);
        accA = __builtin_amdgcn_mfma_f32_32x32x16_bf16(ca, x4, accA, 0, 0, 0);
        #pragma unroll
        for (int c = 0; c < 4; ++c)
            accB = __builtin_amdgcn_mfma_f32_32x32x16_bf16(ch[c], xl[c], accB, 0, 0, 0);
        #pragma unroll
        for (int c = 0; c < 4; ++c)
            accB = __builtin_amdgcn_mfma_f32_32x32x16_bf16(cl[c], xh[c], accB, 0, 0, 0);
        float tl = -3e38f;
        const int tb = t << 5;
        #pragma unroll
        for (int r = 0; r < 16; ++r) {
            float v = accA[r] + accB[r];      // w = x.c - csum/2
            int k = tb + RC[r] + rh4;
            m2 = fmaxf(m2, fminf(m1, v));
            i1 = (v > m1) ? k : i1;           // strict >: first-max = ref tie-break
            m1 = fmaxf(m1, v);
            tl = fmaxf(tl, v);
        }
        tl = fmaxf(tl, __shfl_xor(tl, 32, 64));
        if (half == 0) tmax[t * 128 + pb] = tl;
    };
    auto load_tile = [&](int t, bf16x8* ch, bf16x8* cl, bf16x8& ca) {
        const bf16x8* bp = base + (size_t)t * 576 + lane;
        #pragma unroll
        for (int c = 0; c < 4; ++c) {
            ch[c] = bp[c * 128];
            cl[c] = bp[c * 128 + 64];
        }
        ca = bp[512];
    };

    bf16x8 chA[4], clA[4], caA, chB[4], clB[4], caB;
    load_tile(0, chA, clA, caA);
    for (int t = 0; t < 32; t += 2) {         // double-buffered tile loop
        load_tile(t + 1, chB, clB, caB);
        screen_tile(t, chA, clA, caA);
        if (t + 2 < 32) load_tile(t + 2, chA, clA, caA);
        screen_tile(t + 1, chB, clB, caB);
    }
    // cross-half merge; ties resolve via ambiguous path
    {
        float m1o = __shfl_xor(m1, 32, 64);
        float m2o = __shfl_xor(m2, 32, 64);
        int   i1o = __shfl_xor(i1, 32, 64);
        m2 = fmaxf(fmaxf(m2, m2o), fminf(m1, m1o));
        i1 = (m1o > m1) ? i1o : i1;
        m1 = fmaxf(m1, m1o);
        if (half == 0) {
            m1f[pb] = m1;
            fk[pb] = i1;
            if (m2 >= m1 - EPS_A_W) {
                int a = atomicAdd(&acount, 1);
                ambig[a] = pb;
            }
        }
    }
    __syncthreads();

    // Exact rescan: one wave per ambiguous point, candidate tiles only.
    // Reference-bit-exact: dist = fl32(fl32(A+csum[k]) - fl32(2*seqFMA)).
    for (int a = wave; a < acount; a += 4) {
        int p = ambig[a];
        const float* xrow = &xs[p * 65];
        float Aq = np_pairwise_sumsq64(xrow);
        float thr = m1f[p] - EPS_T_W;
        unsigned long long best = ~0ULL;
        for (int t = 0; t < 32; ++t) {
            if (tmax[t * 128 + p] < thr) continue;   // wave-uniform branch
            if (lane < 32) {
                int k = (t << 5) + lane;
                const float* crow = cb + (size_t)k * 64;
                float m = 0.0f;
                #pragma unroll
                for (int d = 0; d < 64; ++d) m = __fmaf_rn(xrow[d], crow[d], m);
                float D = __fsub_rn(__fadd_rn(Aq, csum[k]), __fmul_rn(2.0f, m));
                unsigned long long key =
                    ((unsigned long long)__float_as_uint(D) << 10) | (unsigned)k;
                best = (key < best) ? key : best;
            }
        }
        #pragma unroll
        for (int off = 32; off > 0; off >>= 1) {
            unsigned long long o = __shfl_xor(best, off, 64);
            best = (o < best) ? o : best;
        }
        if (lane == 0) fk[p] = (int)(best & 1023ULL);
    }
    __syncthreads();

    // indices + histogram + SSE
    if (tid < 128) {
        int myk = fk[tid];
        out[OUT_I_OFF + n0 + tid] = (float)myk;
        atomicAdd(&hist[myk], 1u);
        const float* crow = cb + (size_t)myk * 64;
        const float* xrow = &xs[tid * 65];
        double e = 0.0;
        #pragma unroll
        for (int d = 0; d < 64; ++d) {
            double df = (double)xrow[d] - (double)crow[d];
            e = fma(df, df, e);
        }
        dred[tid] = e;
    }
    __syncthreads();
    if (tid < 64) {
        double v = dred[tid] + dred[tid + 64];
        #pragma unroll
        for (int off = 32; off > 0; off >>= 1) v += __shfl_down(v, off, 64);
        if (tid == 0) atomicAdd(sse, v);
    }
    // quantized [B,C,H,W]: coalesced 128-float store rows per c
    for (int i = tid; i < 128 * 64; i += 256) {
        int p = i & 127, c = i >> 7;
        out[OUT_Q_OFF + (size_t)b * 65536 + (size_t)c * HW + hw0 + p] =
            cb[(size_t)fk[p] * 64 + c];
    }
}

// Finalize: perplexity from histogram, vq_loss from SSE.
__global__ void vq_final(const unsigned int* __restrict__ hist,
                         const double* __restrict__ sse,
                         float* __restrict__ out) {
    __shared__ double red[256];
    int t = threadIdx.x;
    double s = 0.0;
    for (int i = t; i < K_CODES; i += 256) {
        double p = (double)hist[i] / (double)N_PTS;
        s += p * log(p + 1e-10);
    }
    red[t] = s;
    __syncthreads();
    for (int w = 128; w > 0; w >>= 1) {
        if (t < w) red[t] += red[t + w];
        __syncthreads();
    }
    if (t == 0) {
        out[OUT_P_OFF] = (float)exp(-red[0]);
        out[0] = (float)(1.25 * sse[0] / (double)Q_ELEMS);
    }
}

extern "C" void kernel_launch(void* const* d_in, const int* in_sizes, int n_in,
                              void* d_out, int out_size, void* d_ws, size_t ws_size,
                              hipStream_t stream) {
    const float* latents = (const float*)d_in[0];
    const float* cb      = (const float*)d_in[1];
    float* out = (float*)d_out;
    char* ws = (char*)d_ws;

    unsigned int*   hist = (unsigned int*)(ws + WS_HIST);
    double*         sse  = (double*)(ws + WS_SSE);
    float*          csum = (float*)(ws + WS_CSUM);
    unsigned short* cbp  = (unsigned short*)(ws + WS_CBP);

    hipMemsetAsync(ws, 0, 4096 + 8, stream);  // hist + sse

    vq_prep <<<8, 256, 0, stream>>>(cb, csum, cbp);
    vq_main <<<N_PTS / 128, 256, 0, stream>>>(latents, cb, csum, cbp, hist, sse, out);
    vq_final<<<1, 256, 0, stream>>>(hist, sse, out);
}